// Round 2
// baseline (7041.478 us; speedup 1.0000x reference)
//
#include <hip/hip_runtime.h>
#include <stdint.h>

#define B_SZ 128
#define SEQL 1024
#define EMB  64
#define HID  512
#define VOC  96

// producer->consumer ring
#define PKT_T 11                 // u64 packets per thread (32 bf16 vals, 3 per pkt + tag)
#define PKTS_SLOT (256 * PKT_T)  // 2816 pkts per (rowgroup, slot)
#define SPIN_BUDGET (1 << 22)

typedef __attribute__((ext_vector_type(8))) short bf16x8;
typedef __attribute__((ext_vector_type(4))) float f32x4;

__device__ __forceinline__ float bf2f(ushort u) {
  union { uint32_t i; float f; } c; c.i = ((uint32_t)u) << 16; return c.f;
}
__device__ __forceinline__ ushort f2bf(float f) {
  union { float f; uint32_t i; } c; c.f = f;
  uint32_t u = c.i;
  return (ushort)((u + 0x7fffu + ((u >> 16) & 1u)) >> 16);
}
__device__ __forceinline__ float fast_tanh(float v) {
  float e = __expf(2.0f * v);
  return (e - 1.0f) * __builtin_amdgcn_rcpf(e + 1.0f);
}
__device__ __forceinline__ uint64_t pack3(ushort a, ushort b, ushort c, uint32_t tag) {
  return (uint64_t)a | ((uint64_t)b << 16) | ((uint64_t)c << 32) | ((uint64_t)tag << 48);
}
__device__ __forceinline__ uint64_t pload(const uint64_t* p) {
  return __hip_atomic_load((uint64_t*)p, __ATOMIC_RELAXED, __HIP_MEMORY_SCOPE_SYSTEM);
}
__device__ __forceinline__ void pstore(uint64_t* p, uint64_t v) {
  __hip_atomic_store(p, v, __ATOMIC_RELAXED, __HIP_MEMORY_SCOPE_SYSTEM);
}
__device__ __forceinline__ uint32_t pload32(const uint32_t* p) {
  return __hip_atomic_load((uint32_t*)p, __ATOMIC_RELAXED, __HIP_MEMORY_SCOPE_SYSTEM);
}
__device__ __forceinline__ void pstore32(uint32_t* p, uint32_t v) {
  __hip_atomic_store(p, v, __ATOMIC_RELAXED, __HIP_MEMORY_SCOPE_SYSTEM);
}

// flags[0]=dtype mode (0 bf16 / 1 f32); flags[1]=x stride (1 int32 / 2 int64)
__global__ void detect_kernel(const ushort* __restrict__ emb_u16,
                              const int* __restrict__ x32, int* __restrict__ flags) {
  if (blockIdx.x != 0 || threadIdx.x != 0) return;
  int wild = 0;
  for (int i = 0; i < 256; ++i) {
    ushort u = emb_u16[i];
    int ex = (u >> 7) & 0xFF;
    if (u != 0 && (ex < 96 || ex > 159)) wild++;
  }
  flags[0] = (wild > 8) ? 1 : 0;
  int allz = 1, anynz = 0;
  for (int i = 0; i < 64; ++i) {
    if (x32[2 * i + 1] != 0) allz = 0;
    if (x32[2 * i] != 0) anynz = 1;
  }
  flags[1] = (allz && anynz) ? 2 : 1;
}

// zero the ring + prog so stale tags can never false-match (runs every launch)
__global__ void ring_init(uint64_t* __restrict__ ring, uint32_t* __restrict__ prog,
                          long n) {
  long stride = (long)gridDim.x * blockDim.x;
  for (long i = (long)blockIdx.x * blockDim.x + threadIdx.x; i < n; i += stride)
    ring[i] = 0;
  if (blockIdx.x == 0 && threadIdx.x < 64) prog[threadIdx.x] = 0;
}

// xh table, packed layout: embwf[v*512 + (h&15)*32 + (h>>4)] = emb[v]@W_xh[:,h] + b_h[h]
template <int MODE>
__global__ void prep_embw(const void* __restrict__ embp, const void* __restrict__ wxhp,
                          const void* __restrict__ bhp, const int* __restrict__ flags,
                          float* __restrict__ embwf) {
  if (flags[0] != MODE) return;
  int gt = blockIdx.x * 256 + threadIdx.x;
  int v = gt >> 9, h = gt & 511;
  float s;
  if (MODE == 0) {
    const ushort* emb = (const ushort*)embp;
    const ushort* wxh = (const ushort*)wxhp;
    s = bf2f(((const ushort*)bhp)[h]);
#pragma unroll 8
    for (int e = 0; e < EMB; ++e) s += bf2f(emb[v * EMB + e]) * bf2f(wxh[e * HID + h]);
  } else {
    const float* emb = (const float*)embp;
    const float* wxh = (const float*)wxhp;
    s = ((const float*)bhp)[h];
#pragma unroll 8
    for (int e = 0; e < EMB; ++e) s += emb[v * EMB + e] * wxh[e * HID + h];
  }
  embwf[(size_t)v * HID + (h & 15) * 32 + (h >> 4)] = s;
}

// B-fragment prep for mfma_f32_16x16x32_bf16, layout [nt][kt][lane][8]
template <int MODE>
__global__ void prep_frag(const void* __restrict__ Wp, const int* __restrict__ flags,
                          ushort* __restrict__ out, int ncols) {
  if (flags[0] != MODE) return;
  int t = blockIdx.x * 256 + threadIdx.x;
  int lane = t & 63, kt = (t >> 6) & 15, nt = t >> 10;
  int n = nt * 16 + (lane & 15);
  int k0 = kt * 32 + (lane >> 4) * 8;
  ushort* o = out + (size_t)t * 8;
  if (MODE == 0) {
    const ushort* W = (const ushort*)Wp;
#pragma unroll
    for (int j = 0; j < 8; ++j) o[j] = W[(size_t)(k0 + j) * ncols + n];
  } else {
    const float* W = (const float*)Wp;
#pragma unroll
    for (int j = 0; j < 8; ++j) o[j] = f2bf(W[(size_t)(k0 + j) * ncols + n]);
  }
}

// W_hh register/LDS split: per wave 8 nt-tiles x 16 kt = 128 frags;
// 93 in VGPRs, 35 in LDS (140 KB total LDS-W).
#define REG_KT(nt) ((nt) < 5 ? 12 : 11)
#define RIDX(nt, kt) ((nt) < 5 ? (nt) * 12 + (kt) : 60 + ((nt) - 5) * 11 + (kt))
#define LIDX(nt, kt) ((nt) < 5 ? (nt) * 4 + ((kt) - 12) : 20 + ((nt) - 5) * 5 + ((kt) - 11))
#define NFRAG_LDS 35
#define NFRAG_REG 93

// blocks 0..7: producers (recurrence, CU-local W_hh, no inter-block dependency)
// blocks 8..15: consumers (fc logits from the ring, off the critical path)
template <int MODE>
__global__ __launch_bounds__(256, 1) void rnn_pc(
    const int* __restrict__ x, const void* __restrict__ hiddenp,
    const float* __restrict__ embwf, const ushort* __restrict__ wf,
    const ushort* __restrict__ fwf, const void* __restrict__ fcbp,
    const int* __restrict__ flags, uint64_t* __restrict__ ring,
    uint32_t* __restrict__ prog, void* __restrict__ outp, int rslots) {
  if (flags[0] != MODE) return;
  const int xstr = flags[1];
  const int rmask = rslots - 1;
  // 140 frags * 1 KB = 143360 B + 16 KB h = 159744 B static LDS (cap 163840)
  __shared__ __align__(16) ushort lds_w[140 * 512];
  __shared__ __align__(16) ushort lds_h[16 * 512];  // h in A-frag-linear layout
  const int tid = threadIdx.x;
  const int wid = tid >> 6, lane = tid & 63;
  const int q = lane >> 4, l15 = lane & 15;
  const int rg = blockIdx.x & 7;
  const int rbase = rg * 16;
  const bool producer = (blockIdx.x < 8);
  uint64_t* ringrg = ring + (size_t)rg * rslots * PKTS_SLOT;
  // per-thread h-write base (shorts); value (nt,i) at +((nt>>1)*512+(nt&1)*256+i*8)
  const int hwb = wid * 2048 + q * 32 + (l15 >> 3) * 128 + (l15 & 7);
  const size_t BSLV = (size_t)B_SZ * SEQL * VOC;
  int budget = SPIN_BUDGET;  // bounded spins: starvation -> visible failure, not hang

  if (producer) {
    // ---- stage W_hh: 93 frags/wave -> VGPR, 35 -> LDS (fragment-linear, conflict-free)
    const uint4* Wf4 = (const uint4*)wf;
    bf16x8 Wr[NFRAG_REG];
#pragma unroll
    for (int nt = 0; nt < 8; ++nt) {
#pragma unroll
      for (int kt = 0; kt < 16; ++kt) {
        const uint4* s4 = Wf4 + (((size_t)(8 * wid + nt) * 16 + kt) * 64 + lane);
        if (kt < REG_KT(nt)) {
          Wr[RIDX(nt, kt)] = *(const bf16x8*)s4;
        } else {
          *(uint4*)&lds_w[((size_t)wid * NFRAG_LDS + LIDX(nt, kt)) * 512 + lane * 8] = *s4;
        }
      }
    }
    // ---- stage h_{-1} into lds_h (same mapping as the per-step hv writes)
#pragma unroll
    for (int k = 0; k < 32; ++k) {
      int nt = k >> 2, i = k & 3;
      int r = rbase + q * 4 + i, c = (8 * wid + nt) * 16 + l15;
      ushort v = (MODE == 0) ? ((const ushort*)hiddenp)[(size_t)r * HID + c]
                             : f2bf(((const float*)hiddenp)[(size_t)r * HID + c]);
      lds_h[hwb + (nt >> 1) * 512 + (nt & 1) * 256 + i * 8] = v;
    }
    __syncthreads();

    uint32_t prog_seen = 0;
#pragma unroll 1
    for (int t = 0; t < SEQL; ++t) {
      // early: x gather + packed ew loads (f32, one dwordx4 pair per row)
      int xi[4];
#pragma unroll
      for (int i = 0; i < 4; ++i)
        xi[i] = x[((size_t)(rbase + q * 4 + i) * SEQL + t) * xstr];
      f32x4 er[4][2];
#pragma unroll
      for (int i = 0; i < 4; ++i) {
        const f32x4* ef = (const f32x4*)(embwf + (size_t)xi[i] * HID + l15 * 32 + wid * 8);
        er[i][0] = ef[0];
        er[i][1] = ef[1];
      }
      f32x4 acc[8];
#pragma unroll
      for (int nt = 0; nt < 8; ++nt) acc[nt] = (f32x4){0.f, 0.f, 0.f, 0.f};

      // K loop: conflict-free b128 A reads, 2-deep rotation; W from regs or LDS
      bf16x8 ar0 = *(const bf16x8*)&lds_h[0 * 512 + lane * 8];
      bf16x8 ar1 = *(const bf16x8*)&lds_h[1 * 512 + lane * 8];
#pragma unroll
      for (int kt = 0; kt < 16; ++kt) {
        bf16x8 acur = (kt & 1) ? ar1 : ar0;
        if (kt + 2 < 16) {
          bf16x8 nx = *(const bf16x8*)&lds_h[(kt + 2) * 512 + lane * 8];
          if (kt & 1) ar1 = nx; else ar0 = nx;
        }
#pragma unroll
        for (int nt = 0; nt < 8; ++nt) {
          if (kt >= REG_KT(nt)) {
            bf16x8 b = *(const bf16x8*)
                &lds_w[((size_t)wid * NFRAG_LDS + LIDX(nt, kt)) * 512 + lane * 8];
            acc[nt] = __builtin_amdgcn_mfma_f32_16x16x32_bf16(acur, b, acc[nt], 0, 0, 0);
          } else {
            acc[nt] = __builtin_amdgcn_mfma_f32_16x16x32_bf16(acur, Wr[RIDX(nt, kt)],
                                                              acc[nt], 0, 0, 0);
          }
        }
      }
      // h_t = tanh(acc + xh)
      ushort hv[32];
#pragma unroll
      for (int nt = 0; nt < 8; ++nt)
#pragma unroll
        for (int i = 0; i < 4; ++i)
          hv[nt * 4 + i] = f2bf(fast_tanh(acc[nt][i] + er[i][nt >> 2][nt & 3]));

      // flow control: consumer must have staged step t-rslots before slot reuse
      if (t >= rslots) {
        while ((int)prog_seen <= t - rslots && budget > 0) {
          --budget;
          __builtin_amdgcn_s_sleep(2);
          prog_seen = pload32(prog + rg);
        }
      }
      // publish tagged packets straight from registers
      {
        uint64_t* dst = ringrg + (size_t)(t & rmask) * PKTS_SLOT + (size_t)tid * PKT_T;
        uint32_t tag = (uint32_t)(t + 1);
#pragma unroll
        for (int p = 0; p < 10; ++p)
          pstore(dst + p, pack3(hv[3 * p], hv[3 * p + 1], hv[3 * p + 2], tag));
        pstore(dst + 10, pack3(hv[30], hv[31], 0, tag));
      }
      __syncthreads();  // all a-reads of h_{t-1} done
#pragma unroll
      for (int k = 0; k < 32; ++k) {
        int nt = k >> 2, i = k & 3;
        lds_h[hwb + (nt >> 1) * 512 + (nt & 1) * 256 + i * 8] = hv[k];
      }
      __syncthreads();  // h_t ready
    }
    // ---- final hidden state to out
    {
      int r = tid >> 4, fk = tid & 15;
      if (MODE == 0) {
        ushort vv[32];
#pragma unroll
        for (int cc = 0; cc < 32; ++cc)
          vv[cc] = lds_h[fk * 512 + (r + ((cc >> 3) & 3) * 16) * 8 + (cc & 7)];
        ushort* o = (ushort*)outp + BSLV + (size_t)(rbase + r) * HID + fk * 32;
#pragma unroll
        for (int m = 0; m < 4; ++m) *(uint4*)(o + m * 8) = *(const uint4*)&vv[m * 8];
      } else {
        float* o = (float*)outp + BSLV + (size_t)(rbase + r) * HID + fk * 32;
#pragma unroll
        for (int cc = 0; cc < 32; ++cc)
          o[cc] = bf2f(lds_h[fk * 512 + (r + ((cc >> 3) & 3) * 16) * 8 + (cc & 7)]);
      }
    }
  } else {
    // ---------------- consumer: logits = h_t @ fc_w + fc_b ----------------
    const uint4* Ff4 = (const uint4*)fwf;
    const int base = (wid < 2) ? 2 * wid : wid + 2;  // waves own nt {0,1},{2,3},{4},{5}
    bf16x8 Fc0[16], Fc1[16];
#pragma unroll
    for (int kt = 0; kt < 16; ++kt) {
      Fc0[kt] = *(const bf16x8*)(Ff4 + ((size_t)(base * 16 + kt) * 64 + lane));
      Fc1[kt] = (wid < 2)
                    ? *(const bf16x8*)(Ff4 + ((size_t)((base + 1) * 16 + kt) * 64 + lane))
                    : Fc0[kt];
    }
    float b0 = (MODE == 0) ? bf2f(((const ushort*)fcbp)[base * 16 + l15])
                           : ((const float*)fcbp)[base * 16 + l15];
    float b1 = (wid < 2) ? ((MODE == 0) ? bf2f(((const ushort*)fcbp)[(base + 1) * 16 + l15])
                                        : ((const float*)fcbp)[(base + 1) * 16 + l15])
                         : 0.f;
    ushort* outb = (ushort*)outp;
    float* outf = (float*)outp;
#pragma unroll 1
    for (int t = 0; t < SEQL; ++t) {
      const uint32_t tag = (uint32_t)(t + 1);
      const uint64_t* src =
          ringrg + (size_t)(t & rmask) * PKTS_SLOT + (size_t)tid * PKT_T;
      uint64_t p[PKT_T];
#pragma unroll
      for (int j = 0; j < PKT_T; ++j) p[j] = pload(src + j);
#pragma unroll
      for (int j = 0; j < PKT_T; ++j)
        while ((uint32_t)(p[j] >> 48) != tag && budget > 0) {
          --budget;
          __builtin_amdgcn_s_sleep(1);
          p[j] = pload(src + j);
        }
#pragma unroll
      for (int k = 0; k < 32; ++k) {
        int nt = k >> 2, i = k & 3;
        ushort v = (ushort)(p[k / 3] >> (16 * (k % 3)));
        lds_h[hwb + (nt >> 1) * 512 + (nt & 1) * 256 + i * 8] = v;
      }
      __syncthreads();  // h_t staged; ring slot free
      if (tid == 0) pstore32(prog + rg, (uint32_t)(t + 1));
      f32x4 c0 = {0.f, 0.f, 0.f, 0.f}, c1 = {0.f, 0.f, 0.f, 0.f};
#pragma unroll
      for (int kt = 0; kt < 16; ++kt) {
        bf16x8 a = *(const bf16x8*)&lds_h[kt * 512 + lane * 8];
        c0 = __builtin_amdgcn_mfma_f32_16x16x32_bf16(a, Fc0[kt], c0, 0, 0, 0);
        if (wid < 2)
          c1 = __builtin_amdgcn_mfma_f32_16x16x32_bf16(a, Fc1[kt], c1, 0, 0, 0);
      }
#pragma unroll
      for (int i = 0; i < 4; ++i) {
        size_t row = (size_t)(rbase + q * 4 + i) * SEQL + t;
        float v0 = c0[i] + b0;
        size_t i0 = row * VOC + base * 16 + l15;
        if (MODE == 0) outb[i0] = f2bf(v0); else outf[i0] = v0;
        if (wid < 2) {
          float v1 = c1[i] + b1;
          size_t i1 = row * VOC + (base + 1) * 16 + l15;
          if (MODE == 0) outb[i1] = f2bf(v1); else outf[i1] = v1;
        }
      }
      __syncthreads();  // before next unpack overwrites lds_h
    }
  }
}

extern "C" void kernel_launch(void* const* d_in, const int* in_sizes, int n_in,
                              void* d_out, int out_size, void* d_ws, size_t ws_size,
                              hipStream_t stream) {
  const void* x      = d_in[0];
  const void* hidden = d_in[1];
  const void* emb    = d_in[2];
  const void* wxh    = d_in[3];
  const void* whh    = d_in[4];
  const void* bh     = d_in[5];
  const void* fcw    = d_in[6];
  const void* fcb    = d_in[7];

  char* ws = (char*)d_ws;
  int*      flags  = (int*)ws;                      // 256 B
  float*    embwf  = (float*)(ws + 256);            // 196608 B (packed f32 xh table)
  ushort*   wfrag  = (ushort*)(ws + 196864);        // 524288 B (W_hh frags)
  ushort*   fwfrag = (ushort*)(ws + 721152);        // 98304 B  (fc_w frags)
  uint32_t* prog   = (uint32_t*)(ws + 819456);      // 256 B
  uint64_t* ring   = (uint64_t*)(ws + 819712);      // rslots * 8rg * 22528 B

  // size the ring to the workspace we actually have (ws_size==0 treated as ample)
  const size_t base_need = 819712;
  const size_t slot_bytes = (size_t)8 * PKTS_SLOT * 8;  // 180224 per ring depth
  int rslots;
  if (ws_size == 0 || ws_size >= base_need + 4 * slot_bytes) rslots = 4;
  else if (ws_size >= base_need + 2 * slot_bytes) rslots = 2;
  else return;  // workspace too small: fail visibly, don't fault

  long ring_u64 = (long)8 * rslots * PKTS_SLOT;

  ring_init<<<120, 256, 0, stream>>>(ring, prog, ring_u64);

  detect_kernel<<<1, 64, 0, stream>>>((const ushort*)emb, (const int*)x, flags);

  prep_embw<0><<<192, 256, 0, stream>>>(emb, wxh, bh, flags, embwf);
  prep_embw<1><<<192, 256, 0, stream>>>(emb, wxh, bh, flags, embwf);
  prep_frag<0><<<128, 256, 0, stream>>>(whh, flags, wfrag, HID);
  prep_frag<1><<<128, 256, 0, stream>>>(whh, flags, wfrag, HID);
  prep_frag<0><<<24, 256, 0, stream>>>(fcw, flags, fwfrag, VOC);
  prep_frag<1><<<24, 256, 0, stream>>>(fcw, flags, fwfrag, VOC);

  rnn_pc<0><<<16, 256, 0, stream>>>((const int*)x, hidden, embwf, wfrag, fwfrag, fcb,
                                    flags, ring, prog, d_out, rslots);
  rnn_pc<1><<<16, 256, 0, stream>>>((const int*)x, hidden, embwf, wfrag, fwfrag, fcb,
                                    flags, ring, prog, d_out, rslots);
}